// Round 5
// baseline (205.015 us; speedup 1.0000x reference)
//
#include <hip/hip_runtime.h>
#include <hip/hip_bf16.h>
#include <math.h>

#define D 1024
#define AGENT __HIP_MEMORY_SCOPE_AGENT

using vf4 = __attribute__((ext_vector_type(4))) float;

constexpr float TEMPORAL_DECAY = 0.1f;
constexpr float REL_TERM      = 0.1f;   // RELEVANCE_BOOST * RELEVANCE_SCORE
constexpr float SIM_THRESHOLD = 0.7f;
constexpr float COS_EPS       = 1e-8f;
constexpr float LN_EPS        = 1e-5f;

// Block-wide gate: lane 0 polls (relaxed, device scope), then barrier, then a
// device fence so subsequent reads see the producer phase's stores (G16).
__device__ __forceinline__ void wait_count(unsigned* p, unsigned target) {
    if (threadIdx.x == 0) {
        while (__hip_atomic_load(p, __ATOMIC_RELAXED, AGENT) != target)
            __builtin_amdgcn_s_sleep(8);
    }
    __syncthreads();
    __threadfence();
}

// ---------------------------------------------------------------------------
// One fused kernel. grid = 512 x 256. Roles:
//   bid   0..63 : gemm1 split-K partial  (p1[64][4][1024])
//   bid  64..95 : reduce p1 + bias + ReLU -> LDS -> gemm2 partial (p2[32][4][1024])
//   bid  96..99 : reduce p2 + bias -> LayerNorm -> cos-normalize  (cn[4][1024])
//   ALL blocks  : gate on cn-ready flag, then stream episodes.
// __launch_bounds__(256,2): VGPR<=256 -> >=2 blocks/CU -> all 512 co-resident
// (spin gates are deadlock-free regardless of dispatch order).
// ---------------------------------------------------------------------------
__global__ __launch_bounds__(256, 2) void fused_all(
    const float* __restrict__ ctx, const float* __restrict__ ep,
    const float* __restrict__ el,
    const float* __restrict__ W1, const float* __restrict__ b1,
    const float* __restrict__ W2, const float* __restrict__ b2,
    const float* __restrict__ gg, const float* __restrict__ bbeta,
    float* __restrict__ out, int N,
    float* __restrict__ p1, float* __restrict__ p2, float* __restrict__ cn,
    unsigned* __restrict__ ctl)
{
    const int bid = blockIdx.x, t = threadIdx.x;

    __shared__ float red[2][4][32];
    __shared__ float hs[4][32];
    __shared__ float rs_[2][4];
    __shared__ float rn[4];

    if (bid < 64) {
        // ---- phase 1: gemm1 split-K (16 d-rows per block), W1 read once ----
        const vf4* W4 = (const vf4*)W1;
        vf4 a0 = {0.f,0.f,0.f,0.f}, a1 = a0, a2 = a0, a3 = a0;
#pragma unroll
        for (int i = 0; i < 16; ++i) {
            const int d = bid * 16 + i;
            const vf4 w = W4[d * 256 + t];
            a0 += ctx[0 * D + d] * w;
            a1 += ctx[1 * D + d] * w;
            a2 += ctx[2 * D + d] * w;
            a3 += ctx[3 * D + d] * w;
        }
        vf4* P4 = (vf4*)p1;
        P4[(bid * 4 + 0) * 256 + t] = a0;
        P4[(bid * 4 + 1) * 256 + t] = a1;
        P4[(bid * 4 + 2) * 256 + t] = a2;
        P4[(bid * 4 + 3) * 256 + t] = a3;
        __syncthreads();   // all block stores drained (vmcnt) before release
        if (t == 0) __hip_atomic_fetch_add(&ctl[0], 1u, __ATOMIC_RELEASE, AGENT);
    } else if (bid < 96) {
        // ---- phase 2: reduce p1 + bias + ReLU -> hs; gemm2 split-K ----
        const int s = bid - 64;
        wait_count(&ctl[0], 64);
        {
            const int dd = t & 31, g = t >> 5;
            const int b = g & 3, half = g >> 2;
            const int d = s * 32 + dd;
            float part = 0.f;
#pragma unroll 8
            for (int k = 0; k < 32; ++k)
                part += p1[(((half * 32 + k) * 4) + b) * D + d];
            red[half][b][dd] = part;
        }
        __syncthreads();
        if (t < 128) {
            const int b = t >> 5, dd = t & 31;
            hs[b][dd] = fmaxf(red[0][b][dd] + red[1][b][dd] + b1[s * 32 + dd], 0.f);
        }
        __syncthreads();
        const vf4* W4 = (const vf4*)W2;
        vf4 a0 = {0.f,0.f,0.f,0.f}, a1 = a0, a2 = a0, a3 = a0;
#pragma unroll
        for (int i = 0; i < 32; ++i) {
            const vf4 w = W4[(s * 32 + i) * 256 + t];
            a0 += hs[0][i] * w;
            a1 += hs[1][i] * w;
            a2 += hs[2][i] * w;
            a3 += hs[3][i] * w;
        }
        vf4* P4 = (vf4*)p2;
        P4[(s * 4 + 0) * 256 + t] = a0;
        P4[(s * 4 + 1) * 256 + t] = a1;
        P4[(s * 4 + 2) * 256 + t] = a2;
        P4[(s * 4 + 3) * 256 + t] = a3;
        __syncthreads();
        if (t == 0) __hip_atomic_fetch_add(&ctl[1], 1u, __ATOMIC_RELEASE, AGENT);
    } else if (bid < 100) {
        // ---- phase 3: reduce p2 + bias -> LayerNorm -> cosine-normalize ----
        const int b = bid - 96;
        wait_count(&ctl[1], 32);
        const int lane = t & 63, wid = t >> 6;
        const vf4* P4 = (const vf4*)p2;
        vf4 acc = {0.f,0.f,0.f,0.f};
#pragma unroll 8
        for (int sl = 0; sl < 32; ++sl) acc += P4[(sl * 4 + b) * 256 + t];
        acc += ((const vf4*)b2)[t];

        float s  = acc[0] + acc[1] + acc[2] + acc[3];
        float ss = acc[0]*acc[0] + acc[1]*acc[1] + acc[2]*acc[2] + acc[3]*acc[3];
#pragma unroll
        for (int off = 32; off; off >>= 1) {
            s  += __shfl_xor(s, off, 64);
            ss += __shfl_xor(ss, off, 64);
        }
        if (lane == 0) { rs_[0][wid] = s; rs_[1][wid] = ss; }
        __syncthreads();
        s  = rs_[0][0] + rs_[0][1] + rs_[0][2] + rs_[0][3];
        ss = rs_[1][0] + rs_[1][1] + rs_[1][2] + rs_[1][3];

        const float mu   = s * (1.f / D);
        const float var  = ss * (1.f / D) - mu * mu;
        const float rstd = rsqrtf(var + LN_EPS);

        const vf4 g  = ((const vf4*)gg)[t];
        const vf4 be = ((const vf4*)bbeta)[t];
        vf4 y;
#pragma unroll
        for (int i = 0; i < 4; ++i) y[i] = (acc[i] - mu) * rstd * g[i] + be[i];

        float nsq = y[0]*y[0] + y[1]*y[1] + y[2]*y[2] + y[3]*y[3];
#pragma unroll
        for (int off = 32; off; off >>= 1) nsq += __shfl_xor(nsq, off, 64);
        if (lane == 0) rn[wid] = nsq;
        __syncthreads();
        nsq = rn[0] + rn[1] + rn[2] + rn[3];

        const float inv = 1.f / fmaxf(sqrtf(nsq), COS_EPS);
        vf4 o;
#pragma unroll
        for (int i = 0; i < 4; ++i) o[i] = y[i] * inv;
        ((vf4*)(cn + b * D))[t] = o;
        __syncthreads();
        if (t == 0) __hip_atomic_fetch_add(&ctl[2], 1u, __ATOMIC_RELEASE, AGENT);
    }

    // ---- phase 4 (everyone): wait for cn, then stream episodes ----
    wait_count(&ctl[2], 4);

    const int lane = threadIdx.x & 63;
    const int wave = (bid * 256 + t) >> 6;
    const int nw   = (gridDim.x * 256) >> 6;

    const vf4* c4 = (const vf4*)cn;
    vf4 c[4][4];
#pragma unroll
    for (int b = 0; b < 4; ++b)
#pragma unroll
        for (int k = 0; k < 4; ++k) c[b][k] = c4[b * 256 + k * 64 + lane];

    for (int n = wave; n < N; n += 2 * nw) {
        const int  n2    = n + nw;
        const bool have2 = n2 < N;

        const vf4* eA = (const vf4*)(ep + (size_t)n * D);
        const vf4* eB = (const vf4*)(ep + (size_t)n2 * D);

        vf4 ea[4], eb[4];
#pragma unroll
        for (int k = 0; k < 4; ++k) ea[k] = __builtin_nontemporal_load(eA + k * 64 + lane);
        if (have2) {
#pragma unroll
            for (int k = 0; k < 4; ++k) eb[k] = __builtin_nontemporal_load(eB + k * 64 + lane);
        } else {
#pragma unroll
            for (int k = 0; k < 4; ++k) eb[k] = vf4{0.f, 0.f, 0.f, 0.f};
        }

        float a[5]    = {0.f, 0.f, 0.f, 0.f, 0.f};
        float bacc[5] = {0.f, 0.f, 0.f, 0.f, 0.f};
#pragma unroll
        for (int k = 0; k < 4; ++k) {
#pragma unroll
            for (int i = 0; i < 4; ++i) {
                a[4]    = fmaf(ea[k][i], ea[k][i], a[4]);
                bacc[4] = fmaf(eb[k][i], eb[k][i], bacc[4]);
            }
#pragma unroll
            for (int b = 0; b < 4; ++b) {
#pragma unroll
                for (int i = 0; i < 4; ++i) {
                    a[b]    = fmaf(ea[k][i], c[b][k][i], a[b]);
                    bacc[b] = fmaf(eb[k][i], c[b][k][i], bacc[b]);
                }
            }
        }

        // level 32 merges the two rows; 5 more levels finish.
        float m[5];
#pragma unroll
        for (int i = 0; i < 5; ++i) {
            const float tt = __shfl_xor(a[i], 32, 64);
            const float uu = __shfl_xor(bacc[i], 32, 64);
            m[i] = (lane < 32) ? (a[i] + tt) : (bacc[i] + uu);
        }
#pragma unroll
        for (int off = 16; off; off >>= 1)
#pragma unroll
            for (int i = 0; i < 5; ++i) m[i] += __shfl_xor(m[i], off, 64);

        const int half = lane >> 5;
        const int rown = half ? n2 : n;
        if ((lane & 31) < 4 && (half == 0 || have2)) {
            const int   bsel = lane & 3;
            const float sim  = bsel == 0 ? m[0] : bsel == 1 ? m[1] : bsel == 2 ? m[2] : m[3];
            const float inv  = 1.f / fmaxf(sqrtf(m[4]), COS_EPS);
            const float w    = __expf(-TEMPORAL_DECAY * el[rown]) + REL_TERM;
            const float sc   = sim * inv * w;
            out[(size_t)bsel * N + rown] = (sc > SIM_THRESHOLD) ? sc : 0.f;
        }
    }
}

// ---------------------------------------------------------------------------
extern "C" void kernel_launch(void* const* d_in, const int* in_sizes, int n_in,
                              void* d_out, int out_size, void* d_ws, size_t ws_size,
                              hipStream_t stream) {
    const float* ctx = (const float*)d_in[0];
    const float* ep  = (const float*)d_in[1];
    const float* el  = (const float*)d_in[2];
    const float* W1  = (const float*)d_in[3];
    const float* b1  = (const float*)d_in[4];
    const float* W2  = (const float*)d_in[5];
    const float* b2  = (const float*)d_in[6];
    const float* gg  = (const float*)d_in[7];
    const float* bb  = (const float*)d_in[8];
    float* out = (float*)d_out;
    const int N = in_sizes[2];

    float*    base = (float*)d_ws;
    unsigned* ctl  = (unsigned*)base;          // 3 counters (zeroed below)
    float*    p1   = base + 64;                // [64][4][1024] = 1 MB
    float*    p2   = p1 + 64 * 4 * D;          // [32][4][1024] = 512 KB
    float*    cn   = p2 + 32 * 4 * D;          // [4][1024]

    hipMemsetAsync(ctl, 0, 4 * sizeof(unsigned), stream);
    fused_all<<<512, 256, 0, stream>>>(ctx, ep, el, W1, b1, W2, b2, gg, bb,
                                       out, N, p1, p2, cn, ctl);
}

// Round 6
// 165.987 us; speedup vs baseline: 1.2351x; 1.2351x over previous
//
#include <hip/hip_runtime.h>
#include <hip/hip_bf16.h>
#include <math.h>

#define D 1024
#define AGENT __HIP_MEMORY_SCOPE_AGENT

using vf4 = __attribute__((ext_vector_type(4))) float;

constexpr float TEMPORAL_DECAY = 0.1f;
constexpr float REL_TERM      = 0.1f;   // RELEVANCE_BOOST * RELEVANCE_SCORE
constexpr float SIM_THRESHOLD = 0.7f;
constexpr float COS_EPS       = 1e-8f;
constexpr float LN_EPS        = 1e-5f;

__device__ __forceinline__ void wait_count(unsigned* p, unsigned target) {
    if (threadIdx.x == 0) {
        while (__hip_atomic_load(p, __ATOMIC_RELAXED, AGENT) != target)
            __builtin_amdgcn_s_sleep(2);
    }
    __syncthreads();
    __threadfence();
}

// ---------------------------------------------------------------------------
// Fused prologue: 100 blocks x 256. All blocks trivially co-resident.
//   bid  0..63 : p1[s][b][j] = sum_{d in 16-slice} ctx[b][d] * W1[d][j]
//   bid 64..95 : reduce p1 + b1 + ReLU -> LDS -> p2[s][b][j] (gemm2 split-K)
//   bid 96..99 : reduce p2 + b2 -> LayerNorm -> cosine-normalize -> cn[4][1024]
// ---------------------------------------------------------------------------
__global__ __launch_bounds__(256) void prologue_fused(
    const float* __restrict__ ctx,
    const float* __restrict__ W1, const float* __restrict__ b1,
    const float* __restrict__ W2, const float* __restrict__ b2,
    const float* __restrict__ gg, const float* __restrict__ bbeta,
    float* __restrict__ p1, float* __restrict__ p2, float* __restrict__ cn,
    unsigned* __restrict__ ctl)
{
    const int bid = blockIdx.x, t = threadIdx.x;

    if (bid < 64) {
        const vf4* W4 = (const vf4*)W1;
        vf4 a0 = {0.f,0.f,0.f,0.f}, a1 = a0, a2 = a0, a3 = a0;
#pragma unroll
        for (int i = 0; i < 16; ++i) {
            const int d = bid * 16 + i;
            const vf4 w = W4[d * 256 + t];
            a0 += ctx[0 * D + d] * w;
            a1 += ctx[1 * D + d] * w;
            a2 += ctx[2 * D + d] * w;
            a3 += ctx[3 * D + d] * w;
        }
        vf4* P4 = (vf4*)p1;
        P4[(bid * 4 + 0) * 256 + t] = a0;
        P4[(bid * 4 + 1) * 256 + t] = a1;
        P4[(bid * 4 + 2) * 256 + t] = a2;
        P4[(bid * 4 + 3) * 256 + t] = a3;
        __syncthreads();
        if (t == 0) __hip_atomic_fetch_add(&ctl[0], 1u, __ATOMIC_RELEASE, AGENT);
    } else if (bid < 96) {
        const int s = bid - 64;
        __shared__ float red[2][4][32];
        __shared__ float hs[4][32];
        wait_count(&ctl[0], 64);
        {
            const int dd = t & 31, g = t >> 5;
            const int b = g & 3, half = g >> 2;
            const int d = s * 32 + dd;
            float part = 0.f;
#pragma unroll 8
            for (int k = 0; k < 32; ++k)
                part += p1[(((half * 32 + k) * 4) + b) * D + d];
            red[half][b][dd] = part;
        }
        __syncthreads();
        if (t < 128) {
            const int b = t >> 5, dd = t & 31;
            hs[b][dd] = fmaxf(red[0][b][dd] + red[1][b][dd] + b1[s * 32 + dd], 0.f);
        }
        __syncthreads();
        const vf4* W4 = (const vf4*)W2;
        vf4 a0 = {0.f,0.f,0.f,0.f}, a1 = a0, a2 = a0, a3 = a0;
#pragma unroll
        for (int i = 0; i < 32; ++i) {
            const vf4 w = W4[(s * 32 + i) * 256 + t];
            a0 += hs[0][i] * w;
            a1 += hs[1][i] * w;
            a2 += hs[2][i] * w;
            a3 += hs[3][i] * w;
        }
        vf4* P4 = (vf4*)p2;
        P4[(s * 4 + 0) * 256 + t] = a0;
        P4[(s * 4 + 1) * 256 + t] = a1;
        P4[(s * 4 + 2) * 256 + t] = a2;
        P4[(s * 4 + 3) * 256 + t] = a3;
        __syncthreads();
        if (t == 0) __hip_atomic_fetch_add(&ctl[1], 1u, __ATOMIC_RELEASE, AGENT);
    } else {
        const int b = bid - 96;
        __shared__ float rs_[2][4];
        __shared__ float rn[4];
        wait_count(&ctl[1], 32);
        const int lane = t & 63, wid = t >> 6;
        const vf4* P4 = (const vf4*)p2;
        vf4 acc = {0.f,0.f,0.f,0.f};
#pragma unroll 8
        for (int sl = 0; sl < 32; ++sl) acc += P4[(sl * 4 + b) * 256 + t];
        acc += ((const vf4*)b2)[t];

        float s  = acc[0] + acc[1] + acc[2] + acc[3];
        float ss = acc[0]*acc[0] + acc[1]*acc[1] + acc[2]*acc[2] + acc[3]*acc[3];
#pragma unroll
        for (int off = 32; off; off >>= 1) {
            s  += __shfl_xor(s, off, 64);
            ss += __shfl_xor(ss, off, 64);
        }
        if (lane == 0) { rs_[0][wid] = s; rs_[1][wid] = ss; }
        __syncthreads();
        s  = rs_[0][0] + rs_[0][1] + rs_[0][2] + rs_[0][3];
        ss = rs_[1][0] + rs_[1][1] + rs_[1][2] + rs_[1][3];

        const float mu   = s * (1.f / D);
        const float var  = ss * (1.f / D) - mu * mu;
        const float rstd = rsqrtf(var + LN_EPS);

        const vf4 g  = ((const vf4*)gg)[t];
        const vf4 be = ((const vf4*)bbeta)[t];
        vf4 y;
#pragma unroll
        for (int i = 0; i < 4; ++i) y[i] = (acc[i] - mu) * rstd * g[i] + be[i];

        float nsq = y[0]*y[0] + y[1]*y[1] + y[2]*y[2] + y[3]*y[3];
#pragma unroll
        for (int off = 32; off; off >>= 1) nsq += __shfl_xor(nsq, off, 64);
        if (lane == 0) rn[wid] = nsq;
        __syncthreads();
        nsq = rn[0] + rn[1] + rn[2] + rn[3];

        const float inv = 1.f / fmaxf(sqrtf(nsq), COS_EPS);
        vf4 o;
#pragma unroll
        for (int i = 0; i < 4; ++i) o[i] = y[i] * inv;
        ((vf4*)(cn + b * D))[t] = o;
    }
}

// ---------------------------------------------------------------------------
// Streaming pass — byte-identical to R4's score_kernel.
// ---------------------------------------------------------------------------
__global__ __launch_bounds__(256) void score_kernel(const float* __restrict__ ep,
                                                    const float* __restrict__ elapsed,
                                                    const float* __restrict__ ctxn,
                                                    float* __restrict__ out, int N) {
    const int lane = threadIdx.x & 63;
    const int wave = (blockIdx.x * 256 + threadIdx.x) >> 6;
    const int nw   = (gridDim.x * 256) >> 6;

    const vf4* c4 = (const vf4*)ctxn;
    vf4 c[4][4];
#pragma unroll
    for (int b = 0; b < 4; ++b)
#pragma unroll
        for (int k = 0; k < 4; ++k) c[b][k] = c4[b * 256 + k * 64 + lane];

    for (int n = wave; n < N; n += 2 * nw) {
        const int  n2    = n + nw;
        const bool have2 = n2 < N;

        const vf4* eA = (const vf4*)(ep + (size_t)n * D);
        const vf4* eB = (const vf4*)(ep + (size_t)n2 * D);

        vf4 ea[4], eb[4];
#pragma unroll
        for (int k = 0; k < 4; ++k) ea[k] = __builtin_nontemporal_load(eA + k * 64 + lane);
        if (have2) {
#pragma unroll
            for (int k = 0; k < 4; ++k) eb[k] = __builtin_nontemporal_load(eB + k * 64 + lane);
        } else {
#pragma unroll
            for (int k = 0; k < 4; ++k) eb[k] = vf4{0.f, 0.f, 0.f, 0.f};
        }

        float a[5]    = {0.f, 0.f, 0.f, 0.f, 0.f};
        float bacc[5] = {0.f, 0.f, 0.f, 0.f, 0.f};
#pragma unroll
        for (int k = 0; k < 4; ++k) {
#pragma unroll
            for (int i = 0; i < 4; ++i) {
                a[4]    = fmaf(ea[k][i], ea[k][i], a[4]);
                bacc[4] = fmaf(eb[k][i], eb[k][i], bacc[4]);
            }
#pragma unroll
            for (int b = 0; b < 4; ++b) {
#pragma unroll
                for (int i = 0; i < 4; ++i) {
                    a[b]    = fmaf(ea[k][i], c[b][k][i], a[b]);
                    bacc[b] = fmaf(eb[k][i], c[b][k][i], bacc[b]);
                }
            }
        }

        float m[5];
#pragma unroll
        for (int i = 0; i < 5; ++i) {
            const float tt = __shfl_xor(a[i], 32, 64);
            const float uu = __shfl_xor(bacc[i], 32, 64);
            m[i] = (lane < 32) ? (a[i] + tt) : (bacc[i] + uu);
        }
#pragma unroll
        for (int off = 16; off; off >>= 1)
#pragma unroll
            for (int i = 0; i < 5; ++i) m[i] += __shfl_xor(m[i], off, 64);

        const int half = lane >> 5;
        const int rown = half ? n2 : n;
        if ((lane & 31) < 4 && (half == 0 || have2)) {
            const int   bsel = lane & 3;
            const float sim  = bsel == 0 ? m[0] : bsel == 1 ? m[1] : bsel == 2 ? m[2] : m[3];
            const float inv  = 1.f / fmaxf(sqrtf(m[4]), COS_EPS);
            const float w    = __expf(-TEMPORAL_DECAY * elapsed[rown]) + REL_TERM;
            const float sc   = sim * inv * w;
            out[(size_t)bsel * N + rown] = (sc > SIM_THRESHOLD) ? sc : 0.f;
        }
    }
}

// ---------------------------------------------------------------------------
extern "C" void kernel_launch(void* const* d_in, const int* in_sizes, int n_in,
                              void* d_out, int out_size, void* d_ws, size_t ws_size,
                              hipStream_t stream) {
    const float* ctx = (const float*)d_in[0];
    const float* ep  = (const float*)d_in[1];
    const float* el  = (const float*)d_in[2];
    const float* W1  = (const float*)d_in[3];
    const float* b1  = (const float*)d_in[4];
    const float* W2  = (const float*)d_in[5];
    const float* b2  = (const float*)d_in[6];
    const float* gg  = (const float*)d_in[7];
    const float* bb  = (const float*)d_in[8];
    float* out = (float*)d_out;
    const int N = in_sizes[2];

    float*    base = (float*)d_ws;
    unsigned* ctl  = (unsigned*)base;          // 2 counters
    float*    p1   = base + 64;                // [64][4][1024] = 1 MB
    float*    p2   = p1 + 64 * 4 * D;          // [32][4][1024] = 512 KB
    float*    cn   = p2 + 32 * 4 * D;          // [4][1024]

    hipMemsetAsync(ctl, 0, 2 * sizeof(unsigned), stream);
    prologue_fused<<<100, 256, 0, stream>>>(ctx, W1, b1, W2, b2, gg, bb,
                                            p1, p2, cn, ctl);
    score_kernel<<<1024, 256, 0, stream>>>(ep, el, cn, out, N);
}

// Round 7
// 153.299 us; speedup vs baseline: 1.3374x; 1.0828x over previous
//
#include <hip/hip_runtime.h>
#include <hip/hip_bf16.h>
#include <math.h>

#define D 1024

using vf4 = __attribute__((ext_vector_type(4))) float;

constexpr float TEMPORAL_DECAY = 0.1f;
constexpr float REL_TERM      = 0.1f;   // RELEVANCE_BOOST * RELEVANCE_SCORE
constexpr float SIM_THRESHOLD = 0.7f;
constexpr float COS_EPS       = 1e-8f;
constexpr float LN_EPS        = 1e-5f;

// ---------------------------------------------------------------------------
// K1: gemm1 split-K partial. p1[s][b][j] = sum_{d in 16-slice s} X[b][d]*W1[d][j]
// grid = 64, block = 256. W1 read exactly once, coalesced vf4 over j.
// ---------------------------------------------------------------------------
__global__ __launch_bounds__(256) void g1_partial(const float* __restrict__ X,
                                                  const float* __restrict__ W,
                                                  float* __restrict__ p1) {
    const int s = blockIdx.x, t = threadIdx.x;
    const vf4* W4 = (const vf4*)W;
    vf4 a0 = {0.f, 0.f, 0.f, 0.f}, a1 = a0, a2 = a0, a3 = a0;
#pragma unroll
    for (int i = 0; i < 16; ++i) {
        const int d = s * 16 + i;
        const vf4 w = W4[d * 256 + t];
        a0 += X[0 * D + d] * w;
        a1 += X[1 * D + d] * w;
        a2 += X[2 * D + d] * w;
        a3 += X[3 * D + d] * w;
    }
    vf4* P4 = (vf4*)p1;
    P4[(s * 4 + 0) * 256 + t] = a0;
    P4[(s * 4 + 1) * 256 + t] = a1;
    P4[(s * 4 + 2) * 256 + t] = a2;
    P4[(s * 4 + 3) * 256 + t] = a3;
}

// ---------------------------------------------------------------------------
// K2: fused [reduce p1 + bias + ReLU] -> hs (LDS) -> gemm2 split-K partial.
// grid = 32, block = 256.
// ---------------------------------------------------------------------------
__global__ __launch_bounds__(256) void g2_fused(const float* __restrict__ p1,
                                                const float* __restrict__ bias,
                                                const float* __restrict__ W,
                                                float* __restrict__ p2) {
    const int s = blockIdx.x, t = threadIdx.x;
    __shared__ float red[2][4][32];
    __shared__ float hs[4][32];

    {
        const int dd = t & 31, g = t >> 5;
        const int b = g & 3, half = g >> 2;
        const int d = s * 32 + dd;
        float part = 0.f;
#pragma unroll 8
        for (int k = 0; k < 32; ++k)
            part += p1[(((half * 32 + k) * 4) + b) * D + d];
        red[half][b][dd] = part;
    }
    __syncthreads();
    if (t < 128) {
        const int b = t >> 5, dd = t & 31;
        const float h = red[0][b][dd] + red[1][b][dd] + bias[s * 32 + dd];
        hs[b][dd] = fmaxf(h, 0.f);
    }
    __syncthreads();

    const vf4* W4 = (const vf4*)W;
    vf4 a0 = {0.f, 0.f, 0.f, 0.f}, a1 = a0, a2 = a0, a3 = a0;
#pragma unroll
    for (int i = 0; i < 32; ++i) {
        const vf4 w = W4[(s * 32 + i) * 256 + t];
        a0 += hs[0][i] * w;
        a1 += hs[1][i] * w;
        a2 += hs[2][i] * w;
        a3 += hs[3][i] * w;
    }
    vf4* P4 = (vf4*)p2;
    P4[(s * 4 + 0) * 256 + t] = a0;
    P4[(s * 4 + 1) * 256 + t] = a1;
    P4[(s * 4 + 2) * 256 + t] = a2;
    P4[(s * 4 + 3) * 256 + t] = a3;
}

// ---------------------------------------------------------------------------
// K3: reduce p2 (32 slices) + bias -> LayerNorm -> cosine pre-normalization.
// grid = 4, block = 1024, thread owns column j.
// ---------------------------------------------------------------------------
__global__ __launch_bounds__(1024) void ln_cos_fused(const float* __restrict__ p2,
                                                     const float* __restrict__ bias,
                                                     const float* __restrict__ gamma,
                                                     const float* __restrict__ beta,
                                                     float* __restrict__ out) {
    const int b = blockIdx.x, j = threadIdx.x;
    const int lane = j & 63, wid = j >> 6;

    float h = 0.f;
#pragma unroll 8
    for (int sl = 0; sl < 32; ++sl) h += p2[(sl * 4 + b) * D + j];
    h += bias[j];

    float s = h, ss = h * h;
    __shared__ float rs[16], rss[16];
#pragma unroll
    for (int off = 32; off; off >>= 1) {
        s  += __shfl_xor(s, off, 64);
        ss += __shfl_xor(ss, off, 64);
    }
    if (lane == 0) { rs[wid] = s; rss[wid] = ss; }
    __syncthreads();
    s = 0.f; ss = 0.f;
#pragma unroll
    for (int k = 0; k < 16; ++k) { s += rs[k]; ss += rss[k]; }

    const float mu   = s * (1.f / D);
    const float var  = ss * (1.f / D) - mu * mu;
    const float rstd = rsqrtf(var + LN_EPS);
    const float y    = (h - mu) * rstd * gamma[j] + beta[j];

    float nsq = y * y;
    __shared__ float rn[16];
#pragma unroll
    for (int off = 32; off; off >>= 1) nsq += __shfl_xor(nsq, off, 64);
    __syncthreads();
    if (lane == 0) rn[wid] = nsq;
    __syncthreads();
    nsq = 0.f;
#pragma unroll
    for (int k = 0; k < 16; ++k) nsq += rn[k];

    const float inv = 1.f / fmaxf(sqrtf(nsq), COS_EPS);
    out[b * D + j] = y * inv;
}

// ---------------------------------------------------------------------------
// K4 streaming pass, adjacent-pair version: wave handles rows (n, n+1) —
// 8 KB contiguous loads, and the two stores per bsel land in the SAME 64B
// line (4 lines/iter instead of 8). Branch-free inner loop (N even).
// ---------------------------------------------------------------------------
__global__ __launch_bounds__(256) void score_kernel(const float* __restrict__ ep,
                                                    const float* __restrict__ elapsed,
                                                    const float* __restrict__ ctxn,
                                                    float* __restrict__ out, int N) {
    const int lane = threadIdx.x & 63;
    const int wave = (blockIdx.x * 256 + threadIdx.x) >> 6;
    const int nw   = (gridDim.x * 256) >> 6;

    const vf4* c4 = (const vf4*)ctxn;
    vf4 c[4][4];
#pragma unroll
    for (int b = 0; b < 4; ++b)
#pragma unroll
        for (int k = 0; k < 4; ++k) c[b][k] = c4[b * 256 + k * 64 + lane];

    const int nPair = N & ~1;
    for (int n = 2 * wave; n < nPair; n += 2 * nw) {
        const vf4* eA = (const vf4*)(ep + (size_t)n * D);   // row n
        const vf4* eB = eA + 256;                           // row n+1 (contig)

        vf4 ea[4], eb[4];
#pragma unroll
        for (int k = 0; k < 4; ++k) {
            ea[k] = __builtin_nontemporal_load(eA + k * 64 + lane);
            eb[k] = __builtin_nontemporal_load(eB + k * 64 + lane);
        }

        float a[5]    = {0.f, 0.f, 0.f, 0.f, 0.f};
        float bacc[5] = {0.f, 0.f, 0.f, 0.f, 0.f};
#pragma unroll
        for (int k = 0; k < 4; ++k) {
#pragma unroll
            for (int i = 0; i < 4; ++i) {
                a[4]    = fmaf(ea[k][i], ea[k][i], a[4]);
                bacc[4] = fmaf(eb[k][i], eb[k][i], bacc[4]);
            }
#pragma unroll
            for (int b = 0; b < 4; ++b) {
#pragma unroll
                for (int i = 0; i < 4; ++i) {
                    a[b]    = fmaf(ea[k][i], c[b][k][i], a[b]);
                    bacc[b] = fmaf(eb[k][i], c[b][k][i], bacc[b]);
                }
            }
        }

        // level 32 merges the two rows; 5 more levels finish within halves.
        float m[5];
#pragma unroll
        for (int i = 0; i < 5; ++i) {
            const float tt = __shfl_xor(a[i], 32, 64);
            const float uu = __shfl_xor(bacc[i], 32, 64);
            m[i] = (lane < 32) ? (a[i] + tt) : (bacc[i] + uu);
        }
#pragma unroll
        for (int off = 16; off; off >>= 1)
#pragma unroll
            for (int i = 0; i < 5; ++i) m[i] += __shfl_xor(m[i], off, 64);

        // lanes 0..3 -> row n, lanes 32..35 -> row n+1 (same 64B line per bsel)
        const int rown = n + (lane >> 5);
        if ((lane & 31) < 4) {
            const int   bsel = lane & 3;
            const float sim  = bsel == 0 ? m[0] : bsel == 1 ? m[1] : bsel == 2 ? m[2] : m[3];
            const float inv  = 1.f / fmaxf(sqrtf(m[4]), COS_EPS);
            const float w    = __expf(-TEMPORAL_DECAY * elapsed[rown]) + REL_TERM;
            const float sc   = sim * inv * w;
            out[(size_t)bsel * N + rown] = (sc > SIM_THRESHOLD) ? sc : 0.f;
        }
    }

    // odd-N tail (dead at N=200000, kept for safety)
    if (N & 1) {
        const int last = N - 1;
        if ((unsigned)(last >> 1) % (unsigned)nw == (unsigned)wave) {
            const vf4* eA = (const vf4*)(ep + (size_t)last * D);
            float a[5] = {0.f, 0.f, 0.f, 0.f, 0.f};
#pragma unroll
            for (int k = 0; k < 4; ++k) {
                const vf4 e = eA[k * 64 + lane];
#pragma unroll
                for (int i = 0; i < 4; ++i) {
                    a[4] = fmaf(e[i], e[i], a[4]);
#pragma unroll
                    for (int b = 0; b < 4; ++b)
                        a[b] = fmaf(e[i], c[b][k][i], a[b]);
                }
            }
#pragma unroll
            for (int off = 32; off; off >>= 1)
#pragma unroll
                for (int i = 0; i < 5; ++i) a[i] += __shfl_xor(a[i], off, 64);
            if (lane < 4) {
                const float inv = 1.f / fmaxf(sqrtf(a[4]), COS_EPS);
                const float w   = __expf(-TEMPORAL_DECAY * elapsed[last]) + REL_TERM;
                const float sc  = a[lane] * inv * w;
                out[(size_t)lane * N + last] = (sc > SIM_THRESHOLD) ? sc : 0.f;
            }
        }
    }
}

// ---------------------------------------------------------------------------
extern "C" void kernel_launch(void* const* d_in, const int* in_sizes, int n_in,
                              void* d_out, int out_size, void* d_ws, size_t ws_size,
                              hipStream_t stream) {
    const float* ctx = (const float*)d_in[0];
    const float* ep  = (const float*)d_in[1];
    const float* el  = (const float*)d_in[2];
    const float* W1  = (const float*)d_in[3];
    const float* b1  = (const float*)d_in[4];
    const float* W2  = (const float*)d_in[5];
    const float* b2  = (const float*)d_in[6];
    const float* gg  = (const float*)d_in[7];
    const float* bb  = (const float*)d_in[8];
    float* out = (float*)d_out;
    const int N = in_sizes[2];

    float* p1 = (float*)d_ws;             // [64][4][1024]  = 1 MB
    float* p2 = p1 + 64 * 4 * D;          // [32][4][1024]  = 512 KB
    float* cn = p2 + 32 * 4 * D;          // [4][1024]

    g1_partial<<<64, 256, 0, stream>>>(ctx, W1, p1);
    g2_fused<<<32, 256, 0, stream>>>(p1, b1, W2, p2);
    ln_cos_fused<<<4, 1024, 0, stream>>>(p2, b2, gg, bb, cn);
    score_kernel<<<1024, 256, 0, stream>>>(ep, el, cn, out, N);
}